// Round 1
// baseline (132.295 us; speedup 1.0000x reference)
//
#include <hip/hip_runtime.h>

// Problem constants (from reference): B=256, L=2048, K=8
constexpr int BB = 256;
constexpr int LL = 2048;
constexpr int KK = 8;
constexpr double INV_SQRT2 = 0.7071067811865476;
constexpr int THREADS = 1024;

// Ring: basis (1, x, x2, x3') with multiplication table from _scalar_mul.
// Commutative + associative (it's Z[x]/(x^4+1) in disguise), so a left fold
// over k reproduces associative_scan's last element exactly (all-integer math).
//
// Key identity: 2^minp * sum_l pc*2^(pp-minp) == sum_l pc*2^pp, so the
// whole computation is a per-batch reduction over L. Output (B,2) float32.

__global__ __launch_bounds__(THREADS) void esa_kernel(
    const float4* __restrict__ c1,   // (B*L*K) float4
    const float4* __restrict__ c2,   // (B*L*K) float4
    const int4*  __restrict__ p1,    // (B*L*K) ints viewed as int4: 2 per (b,l)
    const int4*  __restrict__ p2,
    float* __restrict__ out)         // (B,2)
{
    const int b   = blockIdx.x;
    const int tid = threadIdx.x;

    double accR = 0.0, accI = 0.0;

    for (int l = tid; l < LL; l += THREADS) {
        const long long base  = ((long long)b * LL + l) * KK; // float4 index
        const long long pbase = ((long long)b * LL + l) * 2;  // int4 index

        const int4 q1a = p1[pbase], q1b = p1[pbase + 1];
        const int4 q2a = p2[pbase], q2b = p2[pbase + 1];
        const int pw[8] = { q1a.x + q2a.x, q1a.y + q2a.y, q1a.z + q2a.z, q1a.w + q2a.w,
                            q1b.x + q2b.x, q1b.y + q2b.y, q1b.z + q2b.z, q1b.w + q2b.w };

        // running ring product, identity = (1,0,0,0). int32 is exact:
        // per-element bound after pow2-strip is 4; product bound 4*16^7 = 2^30.
        int ra = 1, rb = 0, rc = 0, rd = 0;
        int pp = 0;

        #pragma unroll
        for (int k = 0; k < KK; ++k) {
            const float4 u = c1[base + k];
            const float4 v = c2[base + k];
            const int a1 = (int)u.x, b1 = (int)u.y, g1 = (int)u.z, e1 = (int)u.w;
            const int a2 = (int)v.x, b2 = (int)v.y, g2 = (int)v.z, e2 = (int)v.w;

            // z = scalar_mul(c1,c2)
            int A  = a1*a2 + b1*e2 - g1*g2 + e1*b2;
            int Bv = a1*b2 + b1*a2 + g1*e2 + e1*g2;
            int C  = a1*g2 + b1*b2 + g1*a2 - e1*e2;
            int D  = a1*e2 - b1*g2 - g1*b2 + e1*a2;

            int p = pw[k];

            // strip common powers of 2: while(all even && any nonzero) halve.
            // == shift all by ctz(A|B|C|D) when nonzero (parity via low bit,
            // arithmetic >> matches floor-div for even negatives).
            const int m = A | Bv | C | D;
            if (m != 0) {
                const int s = __builtin_ctz(m);
                A >>= s; Bv >>= s; C >>= s; D >>= s;
                p += s;
            }

            // r = scalar_mul(r, z)
            const int nA = ra*A  + rb*D  - rc*C  + rd*Bv;
            const int nB = ra*Bv + rb*A  + rc*D  + rd*C;
            const int nC = ra*C  + rb*Bv + rc*A  - rd*D;
            const int nD = ra*D  - rb*C  - rc*Bv + rd*A;
            ra = nA; rb = nB; rc = nC; rd = nD;
            pp += p;
        }

        const double s  = ldexp(1.0, pp);
        const double rA = (double)ra, rB = (double)rb, rC = (double)rc, rD = (double)rd;
        accR += (rA + (rB + rD) * INV_SQRT2) * s;
        accI += (rC + (rB - rD) * INV_SQRT2) * s;
    }

    // deterministic block reduction: wave64 shuffle, then LDS across waves
    for (int off = 32; off > 0; off >>= 1) {
        accR += __shfl_down(accR, off, 64);
        accI += __shfl_down(accI, off, 64);
    }
    __shared__ double sR[THREADS / 64], sI[THREADS / 64];
    const int wave = tid >> 6;
    const int lane = tid & 63;
    if (lane == 0) { sR[wave] = accR; sI[wave] = accI; }
    __syncthreads();
    if (tid == 0) {
        double tR = 0.0, tI = 0.0;
        #pragma unroll
        for (int w = 0; w < THREADS / 64; ++w) { tR += sR[w]; tI += sI[w]; }
        out[b * 2 + 0] = (float)tR;
        out[b * 2 + 1] = (float)tI;
    }
}

extern "C" void kernel_launch(void* const* d_in, const int* in_sizes, int n_in,
                              void* d_out, int out_size, void* d_ws, size_t ws_size,
                              hipStream_t stream) {
    const float4* c1 = (const float4*)d_in[0];
    const float4* c2 = (const float4*)d_in[1];
    const int4*   p1 = (const int4*)d_in[2];
    const int4*   p2 = (const int4*)d_in[3];
    float* out = (float*)d_out;

    esa_kernel<<<BB, THREADS, 0, stream>>>(c1, c2, p1, p2, out);
}

// Round 2
// 36.974 us; speedup vs baseline: 3.5781x; 3.5781x over previous
//
#include <hip/hip_runtime.h>

// B=256, L=2048, K=8. Output (B,2) float32.
constexpr int BB = 256;
constexpr int LL = 2048;
constexpr int KK = 8;
constexpr int THREADS = 1024;
constexpr int SPLIT = 2;               // blocks per batch (L split)
constexpr double INV_SQRT2 = 0.7071067811865476;

// Ring = Z[t]/(t^4+1) in basis (1, t, t^2, -t^3): commutative+associative,
// so the k-product can be reduced in any order. All multiplies have
// |operands| <= 2^14 (elementwise bound 4 -> 64 -> 16384 across butterfly
// levels), so __mul24 (v_mul_i32_i24, full-rate) is exact; final components
// bounded by 4*16384^2 = 2^30 < 2^31.
//
// Identity: 2^minp * sum_l pc*2^(pp-minp) == sum_l pc*2^pp  -> pure per-batch
// reduction over L; no cross-l coupling.

__device__ __forceinline__ void ring_mul(int& ra, int& rb, int& rc, int& rd,
                                         int A, int Bv, int C, int D) {
    const int nA = __mul24(ra, A)  + __mul24(rb, D)  - __mul24(rc, C)  + __mul24(rd, Bv);
    const int nB = __mul24(ra, Bv) + __mul24(rb, A)  + __mul24(rc, D)  + __mul24(rd, C);
    const int nC = __mul24(ra, C)  + __mul24(rb, Bv) + __mul24(rc, A)  - __mul24(rd, D);
    const int nD = __mul24(ra, D)  - __mul24(rb, C)  - __mul24(rc, Bv) + __mul24(rd, A);
    ra = nA; rb = nB; rc = nC; rd = nD;
}

// From loaded (u,v,p): form z = scalar_mul, strip powers of 2, butterfly-
// reduce the 8 lanes of the k-group, accumulate (lane k==0 only, via w=0).
__device__ __forceinline__ void process(const float4 u, const float4 v, int p,
                                        const int lane, double& accR, double& accI) {
    const int a1 = (int)u.x, b1 = (int)u.y, g1 = (int)u.z, e1 = (int)u.w;
    const int a2 = (int)v.x, b2 = (int)v.y, g2 = (int)v.z, e2 = (int)v.w;

    int A  = __mul24(a1,a2) + __mul24(b1,e2) - __mul24(g1,g2) + __mul24(e1,b2);
    int Bv = __mul24(a1,b2) + __mul24(b1,a2) + __mul24(g1,e2) + __mul24(e1,g2);
    int C  = __mul24(a1,g2) + __mul24(b1,b2) + __mul24(g1,a2) - __mul24(e1,e2);
    int D  = __mul24(a1,e2) - __mul24(b1,g2) - __mul24(g1,b2) + __mul24(e1,a2);

    // strip common powers of two (ctz of OR; arith >> == floor-div for evens)
    const int m = A | Bv | C | D;
    const int s = (m == 0) ? 0 : __builtin_ctz(m);
    A >>= s; Bv >>= s; C >>= s; D >>= s;
    p += s;

    // butterfly product over the 8-lane k-group (xor 1,2,4)
    #pragma unroll
    for (int off = 1; off < 8; off <<= 1) {
        const int oa = __shfl_xor(A,  off, 64);
        const int ob = __shfl_xor(Bv, off, 64);
        const int oc = __shfl_xor(C,  off, 64);
        const int od = __shfl_xor(D,  off, 64);
        const int op = __shfl_xor(p,  off, 64);
        ring_mul(A, Bv, C, D, oa, ob, oc, od);
        p += op;
    }

    // 2^p (p in [0,32]) via exponent-bit construction; only k==0 lane adds
    const unsigned long long bits = ((unsigned long long)(1023 + p)) << 52;
    const double w = ((lane & 7) == 0) ? __longlong_as_double((long long)bits) : 0.0;
    const double dA = (double)A, dB = (double)Bv, dC = (double)C, dD = (double)D;
    accR += w * (dA + (dB + dD) * INV_SQRT2);
    accI += w * (dC + (dB - dD) * INV_SQRT2);
}

__global__ __launch_bounds__(THREADS) void esa_kernel(
    const float4* __restrict__ c1,
    const float4* __restrict__ c2,
    const int*  __restrict__ p1,
    const int*  __restrict__ p2,
    float* __restrict__ out) {
    const int b    = blockIdx.x >> 1;
    const int half = blockIdx.x & 1;
    const int tid  = threadIdx.x;
    const int wave = tid >> 6;
    const int lane = tid & 63;

    constexpr int LSPAN = LL / SPLIT;          // 1024 l's per block
    constexpr int LPW   = 16;                  // l's per wave per outer iter (2 groups of 8)
    constexpr int LPB   = (THREADS / 64) * LPW;// 256 l's per block per outer iter
    constexpr int ITERS = LSPAN / LPB;         // 4

    double accR = 0.0, accI = 0.0;

    for (int it = 0; it < ITERS; ++it) {
        const int lbase = half * LSPAN + it * LPB + wave * LPW;
        const long long idxA = ((long long)b * LL + lbase) * KK + lane; // 64 consecutive float4
        const long long idxB = idxA + 64;

        // issue all 8 loads first (dense: lane i -> element i)
        const float4 uA = c1[idxA], vA = c2[idxA];
        const float4 uB = c1[idxB], vB = c2[idxB];
        const int    pA = p1[idxA] + p2[idxA];
        const int    pB = p1[idxB] + p2[idxB];

        process(uA, vA, pA, lane, accR, accI);
        process(uB, vB, pB, lane, accR, accI);
    }

    // wave reduce (only lanes with lane%8==0 hold nonzero; sum all 64)
    for (int off = 32; off > 0; off >>= 1) {
        accR += __shfl_down(accR, off, 64);
        accI += __shfl_down(accI, off, 64);
    }
    __shared__ double sR[THREADS / 64], sI[THREADS / 64];
    if (lane == 0) { sR[wave] = accR; sI[wave] = accI; }
    __syncthreads();
    if (tid == 0) {
        double tR = 0.0, tI = 0.0;
        #pragma unroll
        for (int w = 0; w < THREADS / 64; ++w) { tR += sR[w]; tI += sI[w]; }
        // exactly SPLIT=2 commutative float adds per output -> deterministic
        atomicAdd(&out[b * 2 + 0], (float)tR);
        atomicAdd(&out[b * 2 + 1], (float)tI);
    }
}

extern "C" void kernel_launch(void* const* d_in, const int* in_sizes, int n_in,
                              void* d_out, int out_size, void* d_ws, size_t ws_size,
                              hipStream_t stream) {
    const float4* c1 = (const float4*)d_in[0];
    const float4* c2 = (const float4*)d_in[1];
    const int*    p1 = (const int*)d_in[2];
    const int*    p2 = (const int*)d_in[3];
    float* out = (float*)d_out;

    hipMemsetAsync(out, 0, (size_t)out_size * sizeof(float), stream);
    esa_kernel<<<BB * SPLIT, THREADS, 0, stream>>>(c1, c2, p1, p2, out);
}

// Round 3
// 36.406 us; speedup vs baseline: 3.6339x; 1.0156x over previous
//
#include <hip/hip_runtime.h>

// B=256, L=2048, K=8. Output (B,2) float32.
constexpr int BB = 256;
constexpr int LL = 2048;
constexpr int KK = 8;
constexpr int THREADS = 512;
constexpr int SPLIT = 4;               // blocks per batch (L split)
constexpr double INV_SQRT2 = 0.7071067811865476;

// Ring = Z[t]/(t^4+1) in basis (1, t, t^2, -t^3): commutative+associative.
// |z components| <= 4 after pow2-strip; butterfly levels bound 64, 16384;
// __mul24 exact for |operands| <= 2^14, sums <= 2^30 < 2^31.
// Identity: 2^minp * sum_l pc*2^(pp-minp) == sum_l pc*2^pp -> per-batch
// reduction over L, no cross-l coupling.

__device__ __forceinline__ void ring_mul(int& ra, int& rb, int& rc, int& rd,
                                         int A, int Bv, int C, int D) {
    const int nA = __mul24(ra, A)  + __mul24(rb, D)  - __mul24(rc, C)  + __mul24(rd, Bv);
    const int nB = __mul24(ra, Bv) + __mul24(rb, A)  + __mul24(rc, D)  + __mul24(rd, C);
    const int nC = __mul24(ra, C)  + __mul24(rb, Bv) + __mul24(rc, A)  - __mul24(rd, D);
    const int nD = __mul24(ra, D)  - __mul24(rb, C)  - __mul24(rc, Bv) + __mul24(rd, A);
    ra = nA; rb = nB; rc = nC; rd = nD;
}

// lane = l_sub*8 + k within the wave; one call handles 8 l's x 8 k's.
__device__ __forceinline__ void process(const float4 u, const float4 v, int p,
                                        const int lane, double& accR, double& accI) {
    const int a1 = (int)u.x, b1 = (int)u.y, g1 = (int)u.z, e1 = (int)u.w;
    const int a2 = (int)v.x, b2 = (int)v.y, g2 = (int)v.z, e2 = (int)v.w;

    int A  = __mul24(a1,a2) + __mul24(b1,e2) - __mul24(g1,g2) + __mul24(e1,b2);
    int Bv = __mul24(a1,b2) + __mul24(b1,a2) + __mul24(g1,e2) + __mul24(e1,g2);
    int C  = __mul24(a1,g2) + __mul24(b1,b2) + __mul24(g1,a2) - __mul24(e1,e2);
    int D  = __mul24(a1,e2) - __mul24(b1,g2) - __mul24(g1,b2) + __mul24(e1,a2);

    // strip common powers of two
    const int m = A | Bv | C | D;
    const int s = (m == 0) ? 0 : __builtin_ctz(m);
    A >>= s; Bv >>= s; C >>= s; D >>= s;
    p += s;

    // butterfly product over the 8-lane k-group (xor 1,2,4)
    #pragma unroll
    for (int off = 1; off < 8; off <<= 1) {
        const int oa = __shfl_xor(A,  off, 64);
        const int ob = __shfl_xor(Bv, off, 64);
        const int oc = __shfl_xor(C,  off, 64);
        const int od = __shfl_xor(D,  off, 64);
        const int op = __shfl_xor(p,  off, 64);
        ring_mul(A, Bv, C, D, oa, ob, oc, od);
        p += op;
    }

    // 2^p (p in [0,32]) via exponent bits; only the k==0 lane of each group adds
    const unsigned long long bits = ((unsigned long long)(1023 + p)) << 52;
    const double w = ((lane & 7) == 0) ? __longlong_as_double((long long)bits) : 0.0;
    const double dA = (double)A, dB = (double)Bv, dC = (double)C, dD = (double)D;
    accR += w * (dA + (dB + dD) * INV_SQRT2);
    accI += w * (dC + (dB - dD) * INV_SQRT2);
}

__global__ __launch_bounds__(THREADS, 8) void esa_kernel(
    const float4* __restrict__ c1,
    const float4* __restrict__ c2,
    const int*  __restrict__ p1,
    const int*  __restrict__ p2,
    float* __restrict__ out) {
    const int b    = blockIdx.x >> 2;          // SPLIT = 4
    const int part = blockIdx.x & 3;
    const int tid  = threadIdx.x;
    const int wave = tid >> 6;
    const int lane = tid & 63;

    constexpr int LSPAN = LL / SPLIT;                // 512 l's per block
    constexpr int GRP   = 4;                         // process-groups per iter
    constexpr int LPW   = 8 * GRP;                   // 32 l's per wave per iter
    constexpr int LPB   = (THREADS / 64) * LPW;      // 256 l's per block per iter
    constexpr int ITERS = LSPAN / LPB;               // 2

    double accR = 0.0, accI = 0.0;

    for (int it = 0; it < ITERS; ++it) {
        const int lbase = part * LSPAN + it * LPB + wave * LPW;
        const long long i0 = ((long long)b * LL + lbase) * KK + lane;

        // issue ALL loads up front (dense: lane i -> element i, 64x16B per instr)
        float4 u[GRP], v[GRP]; int pw[GRP];
        #pragma unroll
        for (int g = 0; g < GRP; ++g) {
            const long long idx = i0 + (long long)g * 64;
            u[g]  = c1[idx];
            v[g]  = c2[idx];
            pw[g] = p1[idx] + p2[idx];
        }

        #pragma unroll
        for (int g = 0; g < GRP; ++g)
            process(u[g], v[g], pw[g], lane, accR, accI);
    }

    // wave reduce then LDS across waves
    for (int off = 32; off > 0; off >>= 1) {
        accR += __shfl_down(accR, off, 64);
        accI += __shfl_down(accI, off, 64);
    }
    __shared__ double sR[THREADS / 64], sI[THREADS / 64];
    if (lane == 0) { sR[wave] = accR; sI[wave] = accI; }
    __syncthreads();
    if (tid == 0) {
        double tR = 0.0, tI = 0.0;
        #pragma unroll
        for (int w = 0; w < THREADS / 64; ++w) { tR += sR[w]; tI += sI[w]; }
        // SPLIT=4 commutative float adds per output; |order error| << threshold
        atomicAdd(&out[b * 2 + 0], (float)tR);
        atomicAdd(&out[b * 2 + 1], (float)tI);
    }
}

extern "C" void kernel_launch(void* const* d_in, const int* in_sizes, int n_in,
                              void* d_out, int out_size, void* d_ws, size_t ws_size,
                              hipStream_t stream) {
    const float4* c1 = (const float4*)d_in[0];
    const float4* c2 = (const float4*)d_in[1];
    const int*    p1 = (const int*)d_in[2];
    const int*    p2 = (const int*)d_in[3];
    float* out = (float*)d_out;

    hipMemsetAsync(out, 0, (size_t)out_size * sizeof(float), stream);
    esa_kernel<<<BB * SPLIT, THREADS, 0, stream>>>(c1, c2, p1, p2, out);
}